// Round 1
// baseline (369.866 us; speedup 1.0000x reference)
//
#include <hip/hip_runtime.h>
#include <hip/hip_bf16.h>

// Sizes
constexpr int BATCH = 8192;
constexpr int NREAL = 2000;   // real feature / output-col count
constexpr int KSLOT = 2048;   // per-matrix padded K slot
constexpr int KPAD  = 6144;   // 3 * 2048
constexpr int NPAD  = 2048;   // padded N (W_cat rows)

typedef short bf16x8 __attribute__((ext_vector_type(8)));
typedef float f32x4  __attribute__((ext_vector_type(4)));

__device__ inline void gload_lds16(const void* g, void* l) {
  __builtin_amdgcn_global_load_lds(
      (const __attribute__((address_space(1))) unsigned int*)g,
      (__attribute__((address_space(3))) unsigned int*)l,
      16, 0, 0);
}

// manual f32 -> bf16 round-to-nearest-even (avoids header-struct variance)
__device__ inline unsigned short f2bf(float x) {
  union { float f; unsigned int u; } v;
  v.f = x;
  unsigned int r = v.u + 0x7fffu + ((v.u >> 16) & 1u);
  return (unsigned short)(r >> 16);
}

// ---------------------------------------------------------------------------
// Kernel 1: per-row standardize (ddof=1) + bf16 pack into A_cat [8192][6144]
// grid (8192, 3), block 256. mat 0=prev, 1=next, 2=self.
// Each thread t<250 owns 8 consecutive floats; t in [250,256) writes zero pad.
// ---------------------------------------------------------------------------
__global__ __launch_bounds__(256) void std_pack_kernel(
    const float* __restrict__ prev, const float* __restrict__ nxt,
    const float* __restrict__ selfa, unsigned short* __restrict__ Acat) {
  __shared__ float red[4];
  const int row = blockIdx.x;
  const int mat = blockIdx.y;
  const float* src = (mat == 0) ? prev : (mat == 1) ? nxt : selfa;
  const int t = threadIdx.x;

  float x[8];
  float s1 = 0.f;
  if (t < 250) {
    const float4* p = (const float4*)(src + (size_t)row * NREAL + t * 8);
    float4 a = p[0], b = p[1];
    x[0] = a.x; x[1] = a.y; x[2] = a.z; x[3] = a.w;
    x[4] = b.x; x[5] = b.y; x[6] = b.z; x[7] = b.w;
#pragma unroll
    for (int j = 0; j < 8; ++j) s1 += x[j];
  } else {
#pragma unroll
    for (int j = 0; j < 8; ++j) x[j] = 0.f;
  }
#pragma unroll
  for (int o = 32; o; o >>= 1) s1 += __shfl_xor(s1, o);
  if ((t & 63) == 0) red[t >> 6] = s1;
  __syncthreads();
  const float mean = (red[0] + red[1] + red[2] + red[3]) * (1.f / 2000.f);
  __syncthreads();

  float ss = 0.f;
  if (t < 250) {
#pragma unroll
    for (int j = 0; j < 8; ++j) { float d = x[j] - mean; ss += d * d; }
  }
#pragma unroll
  for (int o = 32; o; o >>= 1) ss += __shfl_xor(ss, o);
  if ((t & 63) == 0) red[t >> 6] = ss;
  __syncthreads();
  const float var = (red[0] + red[1] + red[2] + red[3]) * (1.f / 1999.f);
  const float scale = 1.f / (sqrtf(var) + 1e-8f);

  unsigned short o8[8];
  if (t < 250) {
#pragma unroll
    for (int j = 0; j < 8; ++j) o8[j] = f2bf((x[j] - mean) * scale);
  } else {
#pragma unroll
    for (int j = 0; j < 8; ++j) o8[j] = 0;
  }
  uint4 q;
  q.x = (unsigned)o8[0] | ((unsigned)o8[1] << 16);
  q.y = (unsigned)o8[2] | ((unsigned)o8[3] << 16);
  q.z = (unsigned)o8[4] | ((unsigned)o8[5] << 16);
  q.w = (unsigned)o8[6] | ((unsigned)o8[7] << 16);
  *(uint4*)(Acat + (size_t)row * KPAD + mat * KSLOT + t * 8) = q;
}

// ---------------------------------------------------------------------------
// Kernel 2: weight concat + bf16 pack into W_cat [2048][6144]
// grid (2048, 3), block 256. Rows >= 2000 and K pad are zeros.
// ---------------------------------------------------------------------------
__global__ __launch_bounds__(256) void w_pack_kernel(
    const float* __restrict__ fW, const float* __restrict__ bW,
    const float* __restrict__ lW, unsigned short* __restrict__ Wcat) {
  const int s = blockIdx.x;
  const int mat = blockIdx.y;
  const int t = threadIdx.x;
  uint4 q = make_uint4(0, 0, 0, 0);
  if (s < NREAL && t < 250) {
    const float* src = ((mat == 0) ? fW : (mat == 1) ? bW : lW) +
                       (size_t)s * NREAL + t * 8;
    const float4* p = (const float4*)src;
    float4 a = p[0], b = p[1];
    q.x = (unsigned)f2bf(a.x) | ((unsigned)f2bf(a.y) << 16);
    q.y = (unsigned)f2bf(a.z) | ((unsigned)f2bf(a.w) << 16);
    q.z = (unsigned)f2bf(b.x) | ((unsigned)f2bf(b.y) << 16);
    q.w = (unsigned)f2bf(b.z) | ((unsigned)f2bf(b.w) << 16);
  }
  *(uint4*)(Wcat + (size_t)s * KPAD + mat * KSLOT + t * 8) = q;
}

// ---------------------------------------------------------------------------
// Kernel 3: bf16 MFMA GEMM, m97 structure: 128x128 tile, BK=64, 4 waves 2x2,
// global_load_lds width-16 staging, 2-barrier K loop. Fused epilogue:
// +bias(3), relu, out = 0.7*relu + 0.3*self_act.
// grid 1024 (= 64 bm x 16 bn), block 256.
// ---------------------------------------------------------------------------
__global__ __launch_bounds__(256, 2) void gemm_kernel(
    const unsigned short* __restrict__ A,   // [8192][6144] bf16
    const unsigned short* __restrict__ W,   // [2048][6144] bf16
    const float* __restrict__ fb, const float* __restrict__ bb,
    const float* __restrict__ lb,
    const float* __restrict__ selfact,      // [8192][2000] f32
    float* __restrict__ out) {              // [8192][2000] f32
  __shared__ unsigned short As[128 * 64];
  __shared__ unsigned short Bs[128 * 64];

  const int tid  = threadIdx.x;
  const int wave = tid >> 6;
  const int lane = tid & 63;
  const int bm = blockIdx.x >> 4;
  const int bn = blockIdx.x & 15;
  const int wr = wave >> 1;
  const int wc = wave & 1;

  f32x4 acc[4][4] = {};

  const unsigned short* Ab = A + (size_t)(bm * 128) * KPAD;
  const unsigned short* Bb = W + (size_t)(bn * 128) * KPAD;

  for (int kt = 0; kt < KPAD / 64; ++kt) {
    const int k0 = kt * 64;
    // stage 128x64 bf16 A-tile and B-tile: 1024 16B chunks each, 4/thread
#pragma unroll
    for (int i = 0; i < 4; ++i) {
      const int c = i * 256 + tid;
      const int r = c >> 3;              // tile row
      const int co = (c & 7) * 8;        // k offset within row
      const int ldsoff = (i * 256 + wave * 64) * 8;  // wave-uniform base (elems)
      gload_lds16(Ab + (size_t)r * KPAD + k0 + co, &As[ldsoff]);
      gload_lds16(Bb + (size_t)r * KPAD + k0 + co, &Bs[ldsoff]);
    }
    __syncthreads();
#pragma unroll
    for (int kk = 0; kk < 2; ++kk) {
      bf16x8 af[4], bf[4];
      const int krow = lane & 15;
      const int kcol = kk * 32 + (lane >> 4) * 8;
#pragma unroll
      for (int m = 0; m < 4; ++m)
        af[m] = *(const bf16x8*)&As[(wr * 64 + m * 16 + krow) * 64 + kcol];
#pragma unroll
      for (int n = 0; n < 4; ++n)
        bf[n] = *(const bf16x8*)&Bs[(wc * 64 + n * 16 + krow) * 64 + kcol];
#pragma unroll
      for (int m = 0; m < 4; ++m)
#pragma unroll
        for (int n = 0; n < 4; ++n)
          acc[m][n] = __builtin_amdgcn_mfma_f32_16x16x32_bf16(
              af[m], bf[n], acc[m][n], 0, 0, 0);
    }
    __syncthreads();
  }

  // epilogue: C/D layout col=lane&15, row=(lane>>4)*4+reg
  const int colLane = lane & 15;
  const int rowGrp  = (lane >> 4) * 4;
#pragma unroll
  for (int n = 0; n < 4; ++n) {
    const int col = bn * 128 + wc * 64 + n * 16 + colLane;
    if (col < NREAL) {
      const float bias = fb[col] + bb[col] + lb[col];
#pragma unroll
      for (int m = 0; m < 4; ++m) {
        const int row0 = bm * 128 + wr * 64 + m * 16 + rowGrp;
#pragma unroll
        for (int r = 0; r < 4; ++r) {
          const float pre = acc[m][n][r] + bias;
          const size_t oi = (size_t)(row0 + r) * NREAL + col;
          out[oi] = 0.7f * fmaxf(pre, 0.f) + 0.3f * selfact[oi];
        }
      }
    }
  }
}

// ---------------------------------------------------------------------------
extern "C" void kernel_launch(void* const* d_in, const int* in_sizes, int n_in,
                              void* d_out, int out_size, void* d_ws,
                              size_t ws_size, hipStream_t stream) {
  const float* prev = (const float*)d_in[0];
  const float* selfa = (const float*)d_in[1];
  const float* nxt  = (const float*)d_in[2];
  const float* fW = (const float*)d_in[3];
  const float* fb = (const float*)d_in[4];
  const float* bW = (const float*)d_in[5];
  const float* bb = (const float*)d_in[6];
  const float* lW = (const float*)d_in[7];
  const float* lb = (const float*)d_in[8];
  float* out = (float*)d_out;

  unsigned short* Acat = (unsigned short*)d_ws;                       // 100.7 MB
  unsigned short* Wcat = Acat + (size_t)BATCH * KPAD;                 // +25.2 MB

  std_pack_kernel<<<dim3(BATCH, 3), 256, 0, stream>>>(prev, nxt, selfa, Acat);
  w_pack_kernel<<<dim3(NPAD, 3), 256, 0, stream>>>(fW, bW, lW, Wcat);
  gemm_kernel<<<dim3(64 * 16), 256, 0, stream>>>(Acat, Wcat, fb, bb, lb,
                                                 selfa, out);
}

// Round 2
// 277.506 us; speedup vs baseline: 1.3328x; 1.3328x over previous
//
#include <hip/hip_runtime.h>
#include <hip/hip_bf16.h>

// Sizes
constexpr int BATCH = 8192;
constexpr int NREAL = 2000;   // real feature / output-col count
constexpr int KSLOT = 2048;   // per-matrix padded K slot
constexpr int KPAD  = 6144;   // 3 * 2048
constexpr int NPAD  = 2048;   // padded N (W_cat rows)
constexpr int NT    = KPAD / 64;  // 96 K-tiles of 64

typedef short bf16x8 __attribute__((ext_vector_type(8)));
typedef float f32x4  __attribute__((ext_vector_type(4)));

__device__ inline void gload_lds16(const void* g, void* l) {
  __builtin_amdgcn_global_load_lds(
      (const __attribute__((address_space(1))) unsigned int*)g,
      (__attribute__((address_space(3))) unsigned int*)l,
      16, 0, 0);
}

__device__ inline unsigned short f2bf(float x) {
  union { float f; unsigned int u; } v;
  v.f = x;
  unsigned int r = v.u + 0x7fffu + ((v.u >> 16) & 1u);
  return (unsigned short)(r >> 16);
}

// ---------------------------------------------------------------------------
// Kernel 1: per-row standardize (ddof=1) + bf16 pack into A_cat [8192][6144]
// ---------------------------------------------------------------------------
__global__ __launch_bounds__(256) void std_pack_kernel(
    const float* __restrict__ prev, const float* __restrict__ nxt,
    const float* __restrict__ selfa, unsigned short* __restrict__ Acat) {
  __shared__ float red[4];
  const int row = blockIdx.x;
  const int mat = blockIdx.y;
  const float* src = (mat == 0) ? prev : (mat == 1) ? nxt : selfa;
  const int t = threadIdx.x;

  float x[8];
  float s1 = 0.f;
  if (t < 250) {
    const float4* p = (const float4*)(src + (size_t)row * NREAL + t * 8);
    float4 a = p[0], b = p[1];
    x[0] = a.x; x[1] = a.y; x[2] = a.z; x[3] = a.w;
    x[4] = b.x; x[5] = b.y; x[6] = b.z; x[7] = b.w;
#pragma unroll
    for (int j = 0; j < 8; ++j) s1 += x[j];
  } else {
#pragma unroll
    for (int j = 0; j < 8; ++j) x[j] = 0.f;
  }
#pragma unroll
  for (int o = 32; o; o >>= 1) s1 += __shfl_xor(s1, o);
  if ((t & 63) == 0) red[t >> 6] = s1;
  __syncthreads();
  const float mean = (red[0] + red[1] + red[2] + red[3]) * (1.f / 2000.f);
  __syncthreads();

  float ss = 0.f;
  if (t < 250) {
#pragma unroll
    for (int j = 0; j < 8; ++j) { float d = x[j] - mean; ss += d * d; }
  }
#pragma unroll
  for (int o = 32; o; o >>= 1) ss += __shfl_xor(ss, o);
  if ((t & 63) == 0) red[t >> 6] = ss;
  __syncthreads();
  const float var = (red[0] + red[1] + red[2] + red[3]) * (1.f / 1999.f);
  const float scale = 1.f / (sqrtf(var) + 1e-8f);

  unsigned short o8[8];
  if (t < 250) {
#pragma unroll
    for (int j = 0; j < 8; ++j) o8[j] = f2bf((x[j] - mean) * scale);
  } else {
#pragma unroll
    for (int j = 0; j < 8; ++j) o8[j] = 0;
  }
  uint4 q;
  q.x = (unsigned)o8[0] | ((unsigned)o8[1] << 16);
  q.y = (unsigned)o8[2] | ((unsigned)o8[3] << 16);
  q.z = (unsigned)o8[4] | ((unsigned)o8[5] << 16);
  q.w = (unsigned)o8[6] | ((unsigned)o8[7] << 16);
  *(uint4*)(Acat + (size_t)row * KPAD + mat * KSLOT + t * 8) = q;
}

// ---------------------------------------------------------------------------
// Kernel 2: weight concat + bf16 pack into W_cat [2048][6144]
// ---------------------------------------------------------------------------
__global__ __launch_bounds__(256) void w_pack_kernel(
    const float* __restrict__ fW, const float* __restrict__ bW,
    const float* __restrict__ lW, unsigned short* __restrict__ Wcat) {
  const int s = blockIdx.x;
  const int mat = blockIdx.y;
  const int t = threadIdx.x;
  uint4 q = make_uint4(0, 0, 0, 0);
  if (s < NREAL && t < 250) {
    const float* src = ((mat == 0) ? fW : (mat == 1) ? bW : lW) +
                       (size_t)s * NREAL + t * 8;
    const float4* p = (const float4*)src;
    float4 a = p[0], b = p[1];
    q.x = (unsigned)f2bf(a.x) | ((unsigned)f2bf(a.y) << 16);
    q.y = (unsigned)f2bf(a.z) | ((unsigned)f2bf(a.w) << 16);
    q.z = (unsigned)f2bf(b.x) | ((unsigned)f2bf(b.y) << 16);
    q.w = (unsigned)f2bf(b.z) | ((unsigned)f2bf(b.w) << 16);
  }
  *(uint4*)(Wcat + (size_t)s * KPAD + mat * KSLOT + t * 8) = q;
}

// ---------------------------------------------------------------------------
// Kernel 3: 256x256 8-phase bf16 MFMA GEMM (T1+T2+T3+T4+T5).
// 512 thr = 8 waves (2M x 4N), per-wave 128x64 out. BK=64 split in 2 K-halves.
// LDS [buf][mat][kkhalf][256][32] bf16, XOR-swizzled 16B chunks.
// Counted vmcnt(6) each phase; drain only in last 2 tiles. Fused epilogue.
// grid 256 (= 32 bm x 8 bn), block 512.
// ---------------------------------------------------------------------------
__global__ __launch_bounds__(512, 2) void gemm_kernel(
    const unsigned short* __restrict__ A,   // [8192][6144] bf16
    const unsigned short* __restrict__ W,   // [2048][6144] bf16
    const float* __restrict__ fb, const float* __restrict__ bb,
    const float* __restrict__ lb,
    const float* __restrict__ selfact,      // [8192][2000] f32
    float* __restrict__ out) {              // [8192][2000] f32
  __shared__ unsigned short lds[2][2][2][256][32];  // 128 KiB
  unsigned short* ldsF = &lds[0][0][0][0][0];

  const int tid  = threadIdx.x;
  const int wave = tid >> 6;
  const int lane = tid & 63;
  const int wm = wave >> 2;     // 0..1
  const int wn = wave & 3;      // 0..3

  // XCD-aware block swizzle (256 blocks, 8 XCDs, 32/XCD, 4 bm-panels each)
  const int nbid = (blockIdx.x & 7) * 32 + (blockIdx.x >> 3);
  const int bm = nbid >> 3;     // 0..31
  const int bn = nbid & 7;      // 0..7

  // staging per-thread source (inverse swizzle): row=tid>>2, pc=tid&3
  const int srow = tid >> 2;
  const int sc = (tid & 3) ^ ((srow >> 1) & 3);
  const unsigned short* Asrc =
      A + (size_t)(bm * 256 + srow) * KPAD + sc * 8;
  const unsigned short* Bsrc =
      W + (size_t)(bn * 256 + srow) * KPAD + sc * 8;

  // fragment read bases (swizzle folds to per-lane constant)
  const int pcx = (lane >> 4) ^ ((lane >> 1) & 3);
  const unsigned short* aF = ldsF + (wm * 128 + (lane & 15)) * 32 + pcx * 8;
  const unsigned short* bF = ldsF + (wn * 64 + (lane & 15)) * 32 + pcx * 8;

  f32x4 acc[8][4] = {};
  bf16x8 bf[4];

#define STAGE(sb, mat, h, tt) { \
    const unsigned short* g_ = ((mat) ? Bsrc : Asrc) + (size_t)(tt) * 64 + (h) * 32; \
    unsigned short* d_ = ldsF + ((sb) * 4 + (mat) * 2 + (h)) * 8192 + wave * 64 * 8; \
    gload_lds16(g_, d_); \
    gload_lds16(g_ + (size_t)128 * KPAD, d_ + 512 * 8); \
  }

#define MFMA16(mh) \
    _Pragma("unroll") for (int fm = 0; fm < 4; ++fm) \
    _Pragma("unroll") for (int fn = 0; fn < 4; ++fn) \
      acc[(mh) * 4 + fm][fn] = __builtin_amdgcn_mfma_f32_16x16x32_bf16( \
          af[fm], bf[fn], acc[(mh) * 4 + fm][fn], 0, 0, 0);

#define PHASE(b, kk, mh, STG, VM) { \
    bf16x8 af[4]; \
    _Pragma("unroll") for (int fm = 0; fm < 4; ++fm) \
      af[fm] = *(const bf16x8*)(aF + ((b) * 4 + (kk)) * 8192 + ((mh) * 64 + fm * 16) * 32); \
    if ((mh) == 0) { \
      _Pragma("unroll") for (int fn = 0; fn < 4; ++fn) \
        bf[fn] = *(const bf16x8*)(bF + ((b) * 4 + 2 + (kk)) * 8192 + (fn * 16) * 32); \
    } \
    STG \
    __builtin_amdgcn_s_barrier(); \
    __builtin_amdgcn_s_setprio(1); \
    MFMA16(mh) \
    __builtin_amdgcn_s_setprio(0); \
    asm volatile("s_waitcnt vmcnt(" VM ")"); \
    __builtin_amdgcn_s_barrier(); \
  }

#define TILE(t, b, VM) { \
    PHASE(b, 0, 0, if ((t) + 1 < NT) STAGE(((b) ^ 1), 0, 1, (t) + 1);, VM) \
    PHASE(b, 0, 1, if ((t) + 1 < NT) STAGE(((b) ^ 1), 1, 1, (t) + 1);, VM) \
    PHASE(b, 1, 0, if ((t) + 2 < NT) STAGE((b), 0, 0, (t) + 2);, VM) \
    PHASE(b, 1, 1, if ((t) + 2 < NT) STAGE((b), 1, 0, (t) + 2);, VM) \
  }

  // Prologue: tile0 all 4 halves + tile1 K-half0 (A,B) = 12 loads/thread
  STAGE(0, 0, 0, 0)   // A kk0 (t0)
  STAGE(0, 1, 0, 0)   // B kk0 (t0)
  STAGE(0, 0, 1, 0)   // A kk1 (t0)
  STAGE(0, 1, 1, 0)   // B kk1 (t0)
  STAGE(1, 0, 0, 1)   // A kk0 (t1)
  STAGE(1, 1, 0, 1)   // B kk0 (t1)
  asm volatile("s_waitcnt vmcnt(8)");   // t0 kk0 halves landed
  __builtin_amdgcn_s_barrier();

  for (int t = 0; t < NT - 2; ++t) {
    const int b = t & 1;
    TILE(t, b, "6")
  }
  TILE(NT - 2, ((NT - 2) & 1), "0")
  TILE(NT - 1, ((NT - 1) & 1), "0")

  // Epilogue: C/D layout col=lane&15, row=(lane>>4)*4+reg
  const int colLane = lane & 15;
  const int rowGrp  = (lane >> 4) * 4;
#pragma unroll
  for (int fn = 0; fn < 4; ++fn) {
    const int col = bn * 256 + wn * 64 + fn * 16 + colLane;
    if (col < NREAL) {
      const float bias = fb[col] + bb[col] + lb[col];
#pragma unroll
      for (int m = 0; m < 8; ++m) {
        const int row0 = bm * 256 + wm * 128 + m * 16 + rowGrp;
#pragma unroll
        for (int r = 0; r < 4; ++r) {
          const float pre = acc[m][fn][r] + bias;
          const size_t oi = (size_t)(row0 + r) * NREAL + col;
          out[oi] = 0.7f * fmaxf(pre, 0.f) + 0.3f * selfact[oi];
        }
      }
    }
  }
#undef TILE
#undef PHASE
#undef MFMA16
#undef STAGE
}

// ---------------------------------------------------------------------------
extern "C" void kernel_launch(void* const* d_in, const int* in_sizes, int n_in,
                              void* d_out, int out_size, void* d_ws,
                              size_t ws_size, hipStream_t stream) {
  const float* prev = (const float*)d_in[0];
  const float* selfa = (const float*)d_in[1];
  const float* nxt  = (const float*)d_in[2];
  const float* fW = (const float*)d_in[3];
  const float* fb = (const float*)d_in[4];
  const float* bW = (const float*)d_in[5];
  const float* bb = (const float*)d_in[6];
  const float* lW = (const float*)d_in[7];
  const float* lb = (const float*)d_in[8];
  float* out = (float*)d_out;

  unsigned short* Acat = (unsigned short*)d_ws;                 // 100.7 MB
  unsigned short* Wcat = Acat + (size_t)BATCH * KPAD;           // +25.2 MB

  std_pack_kernel<<<dim3(BATCH, 3), 256, 0, stream>>>(prev, nxt, selfa, Acat);
  w_pack_kernel<<<dim3(NPAD, 3), 256, 0, stream>>>(fW, bW, lW, Wcat);
  gemm_kernel<<<dim3(32 * 8), 512, 0, stream>>>(Acat, Wcat, fb, bb, lb,
                                                selfa, out);
}

// Round 3
// 267.543 us; speedup vs baseline: 1.3825x; 1.0372x over previous
//
#include <hip/hip_runtime.h>
#include <hip/hip_bf16.h>

// Sizes
constexpr int BATCH = 8192;
constexpr int NREAL = 2000;   // real feature / output-col count
constexpr int KSLOT = 2048;   // per-matrix padded K slot
constexpr int KPAD  = 6144;   // 3 * 2048
constexpr int NPAD  = 2048;   // padded N (W_cat rows)
constexpr int NT    = KPAD / 64;  // 96 K-tiles of 64

typedef short bf16x8 __attribute__((ext_vector_type(8)));
typedef float f32x4  __attribute__((ext_vector_type(4)));

__device__ inline void gload_lds16(const void* g, void* l) {
  __builtin_amdgcn_global_load_lds(
      (const __attribute__((address_space(1))) unsigned int*)g,
      (__attribute__((address_space(3))) unsigned int*)l,
      16, 0, 0);
}

__device__ inline unsigned short f2bf(float x) {
  union { float f; unsigned int u; } v;
  v.f = x;
  unsigned int r = v.u + 0x7fffu + ((v.u >> 16) & 1u);
  return (unsigned short)(r >> 16);
}

// ---------------------------------------------------------------------------
// Kernel 1: fused pack. blockIdx.x < 8192: standardize (ddof=1) activations
// into A_cat [8192][6144]; else weight-concat rows into W_cat [2048][6144].
// grid (8192+2048, 3), block 256.
// ---------------------------------------------------------------------------
__global__ __launch_bounds__(256) void pack_kernel(
    const float* __restrict__ prev, const float* __restrict__ nxt,
    const float* __restrict__ selfa,
    const float* __restrict__ fW, const float* __restrict__ bW,
    const float* __restrict__ lW,
    unsigned short* __restrict__ Acat, unsigned short* __restrict__ Wcat) {
  const int mat = blockIdx.y;
  const int t = threadIdx.x;

  if (blockIdx.x >= BATCH) {
    // ---- weight pack ----
    const int s = blockIdx.x - BATCH;
    uint4 q = make_uint4(0, 0, 0, 0);
    if (s < NREAL && t < 250) {
      const float* src = ((mat == 0) ? fW : (mat == 1) ? bW : lW) +
                         (size_t)s * NREAL + t * 8;
      const float4* p = (const float4*)src;
      float4 a = p[0], b = p[1];
      q.x = (unsigned)f2bf(a.x) | ((unsigned)f2bf(a.y) << 16);
      q.y = (unsigned)f2bf(a.z) | ((unsigned)f2bf(a.w) << 16);
      q.z = (unsigned)f2bf(b.x) | ((unsigned)f2bf(b.y) << 16);
      q.w = (unsigned)f2bf(b.z) | ((unsigned)f2bf(b.w) << 16);
    }
    *(uint4*)(Wcat + (size_t)s * KPAD + mat * KSLOT + t * 8) = q;
    return;
  }

  // ---- standardize pack ----
  __shared__ float red[4];
  const int row = blockIdx.x;
  const float* src = (mat == 0) ? prev : (mat == 1) ? nxt : selfa;

  float x[8];
  float s1 = 0.f;
  if (t < 250) {
    const float4* p = (const float4*)(src + (size_t)row * NREAL + t * 8);
    float4 a = p[0], b = p[1];
    x[0] = a.x; x[1] = a.y; x[2] = a.z; x[3] = a.w;
    x[4] = b.x; x[5] = b.y; x[6] = b.z; x[7] = b.w;
#pragma unroll
    for (int j = 0; j < 8; ++j) s1 += x[j];
  } else {
#pragma unroll
    for (int j = 0; j < 8; ++j) x[j] = 0.f;
  }
#pragma unroll
  for (int o = 32; o; o >>= 1) s1 += __shfl_xor(s1, o);
  if ((t & 63) == 0) red[t >> 6] = s1;
  __syncthreads();
  const float mean = (red[0] + red[1] + red[2] + red[3]) * (1.f / 2000.f);
  __syncthreads();

  float ss = 0.f;
  if (t < 250) {
#pragma unroll
    for (int j = 0; j < 8; ++j) { float d = x[j] - mean; ss += d * d; }
  }
#pragma unroll
  for (int o = 32; o; o >>= 1) ss += __shfl_xor(ss, o);
  if ((t & 63) == 0) red[t >> 6] = ss;
  __syncthreads();
  const float var = (red[0] + red[1] + red[2] + red[3]) * (1.f / 1999.f);
  const float scale = 1.f / (sqrtf(var) + 1e-8f);

  unsigned short o8[8];
  if (t < 250) {
#pragma unroll
    for (int j = 0; j < 8; ++j) o8[j] = f2bf((x[j] - mean) * scale);
  } else {
#pragma unroll
    for (int j = 0; j < 8; ++j) o8[j] = 0;
  }
  uint4 q;
  q.x = (unsigned)o8[0] | ((unsigned)o8[1] << 16);
  q.y = (unsigned)o8[2] | ((unsigned)o8[3] << 16);
  q.z = (unsigned)o8[4] | ((unsigned)o8[5] << 16);
  q.w = (unsigned)o8[6] | ((unsigned)o8[7] << 16);
  *(uint4*)(Acat + (size_t)row * KPAD + mat * KSLOT + t * 8) = q;
}

// ---------------------------------------------------------------------------
// Kernel 2: 256x256 8-phase bf16 MFMA GEMM with register-subtile pipelining.
// 512 thr = 8 waves (2M x 4N), per-wave 128x64 out. BK=64, 2 K-halves.
// LDS [buf][mat][h][256][32] bf16, XOR-swizzled 16B chunks (0 conflicts).
// Each phase: [vmcnt?][barrier][sched_barrier][ds_read NEXT subtile][stage]
// [MFMA on regs loaded LAST phase]. One barrier/phase; vmcnt(2) at ph2/ph4.
// grid 256 (= 32 bm x 8 bn), block 512.
// ---------------------------------------------------------------------------
__global__ __launch_bounds__(512, 2) void gemm_kernel(
    const unsigned short* __restrict__ A,   // [8192][6144] bf16
    const unsigned short* __restrict__ W,   // [2048][6144] bf16
    const float* __restrict__ fb, const float* __restrict__ bb,
    const float* __restrict__ lb,
    const float* __restrict__ selfact,      // [8192][2000] f32
    float* __restrict__ out) {              // [8192][2000] f32
  __shared__ unsigned short lds[2][2][2][256][32];  // 128 KiB
  unsigned short* ldsF = &lds[0][0][0][0][0];

  const int tid  = threadIdx.x;
  const int wave = tid >> 6;
  const int lane = tid & 63;
  const int wm = wave >> 2;     // 0..1
  const int wn = wave & 3;      // 0..3

  // XCD-aware block swizzle (256 blocks, 8 XCDs, 32/XCD, 4 bm-panels each)
  const int nbid = (blockIdx.x & 7) * 32 + (blockIdx.x >> 3);
  const int bm = nbid >> 3;     // 0..31
  const int bn = nbid & 7;      // 0..7

  // staging per-thread source (inverse swizzle): row=tid>>2, pc=tid&3
  const int srow = tid >> 2;
  const int sc = (tid & 3) ^ ((srow >> 1) & 3);
  const unsigned short* Asrc =
      A + (size_t)(bm * 256 + srow) * KPAD + sc * 8;
  const unsigned short* Bsrc =
      W + (size_t)(bn * 256 + srow) * KPAD + sc * 8;

  // fragment read bases (swizzle folds to per-lane constant)
  const int pcx = (lane >> 4) ^ ((lane >> 1) & 3);
  const unsigned short* aF = ldsF + (wm * 128 + (lane & 15)) * 32 + pcx * 8;
  const unsigned short* bF = ldsF + (wn * 64 + (lane & 15)) * 32 + pcx * 8;

  f32x4 acc[8][4] = {};
  bf16x8 afA[4], afB[4], bf0[4], bf1[4];

#define STAGE(sb, mat, h, tt) { \
    const unsigned short* g_ = ((mat) ? Bsrc : Asrc) + (size_t)(tt) * 64 + (h) * 32; \
    unsigned short* d_ = ldsF + ((sb) * 4 + (mat) * 2 + (h)) * 8192 + wave * 64 * 8; \
    gload_lds16(g_, d_); \
    gload_lds16(g_ + (size_t)128 * KPAD, d_ + 512 * 8); \
  }

#define READ_AF(dst, bb, kk, mh) \
    _Pragma("unroll") for (int fm = 0; fm < 4; ++fm) \
      dst[fm] = *(const bf16x8*)(aF + ((bb) * 4 + (kk)) * 8192 + ((mh) * 64 + fm * 16) * 32);

#define READ_BF(dst, bb, kk) \
    _Pragma("unroll") for (int fn = 0; fn < 4; ++fn) \
      dst[fn] = *(const bf16x8*)(bF + ((bb) * 4 + 2 + (kk)) * 8192 + (fn * 16) * 32);

#define MFMA16(afr, bfr, mh) { \
    __builtin_amdgcn_s_setprio(1); \
    _Pragma("unroll") for (int fm = 0; fm < 4; ++fm) \
    _Pragma("unroll") for (int fn = 0; fn < 4; ++fn) \
      acc[(mh) * 4 + fm][fn] = __builtin_amdgcn_mfma_f32_16x16x32_bf16( \
          afr[fm], bfr[fn], acc[(mh) * 4 + fm][fn], 0, 0, 0); \
    __builtin_amdgcn_s_setprio(0); \
  }

  // Prologue: stage all of tile 0; wait its h0; read ph1 subtile.
  STAGE(0, 0, 0, 0)   // A h0 (t0)
  STAGE(0, 1, 0, 0)   // B h0 (t0)
  STAGE(0, 0, 1, 0)   // A h1 (t0)
  STAGE(0, 1, 1, 0)   // B h1 (t0)
  asm volatile("s_waitcnt vmcnt(4)" ::: "memory");  // t0 h0 landed
  __builtin_amdgcn_s_barrier();
  __builtin_amdgcn_sched_barrier(0);
  READ_AF(afA, 0, 0, 0)
  READ_BF(bf0, 0, 0)

  for (int t = 0; t < NT; ++t) {
    const int b = t & 1;
    const bool pf = (t + 1 < NT);
    // ---- ph1: MFMA(kk0,mh0) on afA/bf0; read afB(kk0,mh1); stage A-h0(t+1)
    __builtin_amdgcn_s_barrier();
    __builtin_amdgcn_sched_barrier(0);
    READ_AF(afB, b, 0, 1)
    if (pf) STAGE(b ^ 1, 0, 0, t + 1)
    MFMA16(afA, bf0, 0)
    // ---- ph2: MFMA(kk0,mh1) on afB/bf0; read afA(kk1,mh0)+bf1; stage B-h0
    asm volatile("s_waitcnt vmcnt(2)" ::: "memory");
    __builtin_amdgcn_s_barrier();
    __builtin_amdgcn_sched_barrier(0);
    READ_AF(afA, b, 1, 0)
    READ_BF(bf1, b, 1)
    if (pf) STAGE(b ^ 1, 1, 0, t + 1)
    MFMA16(afB, bf0, 1)
    // ---- ph3: MFMA(kk1,mh0) on afA/bf1; read afB(kk1,mh1); stage A-h1
    __builtin_amdgcn_s_barrier();
    __builtin_amdgcn_sched_barrier(0);
    READ_AF(afB, b, 1, 1)
    if (pf) STAGE(b ^ 1, 0, 1, t + 1)
    MFMA16(afA, bf1, 0)
    // ---- ph4: MFMA(kk1,mh1) on afB/bf1; read next tile's ph1 subtile; stage B-h1
    asm volatile("s_waitcnt vmcnt(2)" ::: "memory");
    __builtin_amdgcn_s_barrier();
    __builtin_amdgcn_sched_barrier(0);
    if (pf) {
      READ_AF(afA, b ^ 1, 0, 0)
      READ_BF(bf0, b ^ 1, 0)
      STAGE(b ^ 1, 1, 1, t + 1)
    }
    MFMA16(afB, bf1, 1)
  }

  // Epilogue: C/D layout col=lane&15, row=(lane>>4)*4+reg
  const int colLane = lane & 15;
  const int rowGrp  = (lane >> 4) * 4;
#pragma unroll
  for (int fn = 0; fn < 4; ++fn) {
    const int col = bn * 256 + wn * 64 + fn * 16 + colLane;
    if (col < NREAL) {
      const float bias = fb[col] + bb[col] + lb[col];
#pragma unroll
      for (int m = 0; m < 8; ++m) {
        const int row0 = bm * 256 + wm * 128 + m * 16 + rowGrp;
#pragma unroll
        for (int r = 0; r < 4; ++r) {
          const float pre = acc[m][fn][r] + bias;
          const size_t oi = (size_t)(row0 + r) * NREAL + col;
          out[oi] = 0.7f * fmaxf(pre, 0.f) + 0.3f * selfact[oi];
        }
      }
    }
  }
#undef MFMA16
#undef READ_BF
#undef READ_AF
#undef STAGE
}

// ---------------------------------------------------------------------------
extern "C" void kernel_launch(void* const* d_in, const int* in_sizes, int n_in,
                              void* d_out, int out_size, void* d_ws,
                              size_t ws_size, hipStream_t stream) {
  const float* prev = (const float*)d_in[0];
  const float* selfa = (const float*)d_in[1];
  const float* nxt  = (const float*)d_in[2];
  const float* fW = (const float*)d_in[3];
  const float* fb = (const float*)d_in[4];
  const float* bW = (const float*)d_in[5];
  const float* bb = (const float*)d_in[6];
  const float* lW = (const float*)d_in[7];
  const float* lb = (const float*)d_in[8];
  float* out = (float*)d_out;

  unsigned short* Acat = (unsigned short*)d_ws;                 // 100.7 MB
  unsigned short* Wcat = Acat + (size_t)BATCH * KPAD;           // +25.2 MB

  pack_kernel<<<dim3(BATCH + NPAD, 3), 256, 0, stream>>>(
      prev, nxt, selfa, fW, bW, lW, Acat, Wcat);
  gemm_kernel<<<dim3(32 * 8), 512, 0, stream>>>(Acat, Wcat, fb, bb, lb,
                                                selfa, out);
}